// Round 9
// baseline (551.893 us; speedup 1.0000x reference)
//
#include <hip/hip_runtime.h>
#include <cstdint>
#include <cmath>

#define B_ 2
#define S_ 2048
#define D_ 2048
#define H_ 16
#define HD_ 128

#define NEG_SENTINEL -1.0e30f

typedef __bf16 bf16;
typedef __attribute__((ext_vector_type(4))) __bf16 bf16x4;
typedef __attribute__((ext_vector_type(8))) __bf16 bf16x8;
typedef __attribute__((ext_vector_type(4))) float f32x4;

__device__ __forceinline__ void gload_lds16(const void* g, void* l) {
  __builtin_amdgcn_global_load_lds(
      (const __attribute__((address_space(1))) unsigned int*)g,
      (__attribute__((address_space(3))) unsigned int*)l, 16, 0, 0);
}

__device__ __forceinline__ f32x4 mfma16(bf16x8 a, bf16x8 b, f32x4 c) {
  return __builtin_amdgcn_mfma_f32_16x16x32_bf16(a, b, c, 0, 0, 0);
}

// ---------------------------------------------------------------------------
// fp32 -> bf16 convert. One thread = 4 elements.
// ---------------------------------------------------------------------------
__global__ __launch_bounds__(256) void cvt_f32_bf16(
    const float* __restrict__ in, bf16* __restrict__ out)
{
  int i = blockIdx.x * 256 + threadIdx.x;
  f32x4 v = ((const f32x4*)in)[i];
  bf16x4 o;
#pragma unroll
  for (int j = 0; j < 4; ++j) o[j] = (bf16)v[j];
  ((bf16x4*)out)[i] = o;
}

// ---------------------------------------------------------------------------
// GEMM: C[m][n] = sum_k A[m][k] * W[n][k], bf16 in, fp32 acc, OT out,
// C row stride ldc (allows fused-QKV output with stride 6144).
// 128x128 tile, BK=64, XOR chunk swizzle. (verified round 3)
// ---------------------------------------------------------------------------
#define GTM 128
#define GTN 128
#define GBK 64

template <typename OT>
__global__ __launch_bounds__(256) void gemm_xwt(
    const bf16* __restrict__ A, const bf16* __restrict__ W, OT* __restrict__ C,
    int M, int N, int K, int ldc)
{
  __shared__ bf16 sA[GTM * GBK];
  __shared__ bf16 sB[GTN * GBK];
  const int tid  = threadIdx.x;
  const int wave = tid >> 6, lane = tid & 63;
  const int quad = lane >> 4, l16 = lane & 15;
  const int tm = blockIdx.y * GTM;
  const int tn = blockIdx.x * GTN;
  const int wm = (wave >> 1) * 64, wn = (wave & 1) * 64;

  f32x4 acc[4][4];
#pragma unroll
  for (int i = 0; i < 4; ++i)
#pragma unroll
    for (int j = 0; j < 4; ++j) acc[i][j] = (f32x4)0.0f;

  for (int k0 = 0; k0 < K; k0 += GBK) {
    __syncthreads();
#pragma unroll
    for (int g = 0; g < 4; ++g) {
      int gb  = (g * 4 + wave) * 64;
      int p   = gb + lane;
      int row = p >> 3, pos = p & 7;
      int cc  = pos ^ (row & 7);
      gload_lds16(A + (size_t)(tm + row) * K + k0 + cc * 8, (char*)sA + (size_t)gb * 16);
      gload_lds16(W + (size_t)(tn + row) * K + k0 + cc * 8, (char*)sB + (size_t)gb * 16);
    }
    __syncthreads();

#pragma unroll
    for (int t = 0; t < 2; ++t) {
      bf16x8 af[4], bfr[4];
#pragma unroll
      for (int i = 0; i < 4; ++i) {
        int rowa = wm + i * 16 + l16;
        int posa = (t * 4 + quad) ^ (rowa & 7);
        af[i] = *(const bf16x8*)(sA + rowa * GBK + posa * 8);
        int rowb = wn + i * 16 + l16;
        int posb = (t * 4 + quad) ^ (rowb & 7);
        bfr[i] = *(const bf16x8*)(sB + rowb * GBK + posb * 8);
      }
#pragma unroll
      for (int i = 0; i < 4; ++i)
#pragma unroll
        for (int j = 0; j < 4; ++j)
          acc[i][j] = mfma16(af[i], bfr[j], acc[i][j]);
    }
  }

#pragma unroll
  for (int i = 0; i < 4; ++i)
#pragma unroll
    for (int r = 0; r < 4; ++r) {
      int row = tm + wm + i * 16 + quad * 4 + r;
#pragma unroll
      for (int j = 0; j < 4; ++j) {
        int col = tn + wn + j * 16 + l16;
        C[(size_t)row * ldc + col] = (OT)acc[i][j][r];
      }
    }
}

// ---------------------------------------------------------------------------
// RoPE in-place; Q pre-scaled by 1/sqrt(HD)*log2(e) (exp2-domain softmax).
// Q/K pointers with row stride rs (supports fused QKV buffer).
// ---------------------------------------------------------------------------
__global__ __launch_bounds__(256) void rope_qk(
    bf16* __restrict__ Q, bf16* __restrict__ Kk,
    const float* __restrict__ cosT, const float* __restrict__ sinT, int rs)
{
  const float kappa = 0.08838834764831845f * 1.4426950408889634f;
  int t = blockIdx.x * 256 + threadIdx.x;
  int d = t & 63;
  int h = (t >> 6) & (H_ - 1);
  int s = (t >> 10) & (S_ - 1);
  int b = t >> 21;
  size_t base = ((size_t)(b * S_ + s)) * rs + (size_t)h * HD_;
  float c1 = cosT[s * HD_ + d];
  float s1 = sinT[s * HD_ + d];
  float c2 = cosT[s * HD_ + d + 64];
  float s2 = sinT[s * HD_ + d + 64];
  {
    float x1 = (float)Q[base + d], x2 = (float)Q[base + d + 64];
    Q[base + d]      = (bf16)((x1 * c1 - x2 * s1) * kappa);
    Q[base + d + 64] = (bf16)((x2 * c2 + x1 * s2) * kappa);
  }
  {
    float x1 = (float)Kk[base + d], x2 = (float)Kk[base + d + 64];
    Kk[base + d]      = (bf16)(x1 * c1 - x2 * s1);
    Kk[base + d + 64] = (bf16)(x2 * c2 + x1 * s2);
  }
}

// ---------------------------------------------------------------------------
// V transpose: V[b][s][...] (row stride rs) -> Vt[(b*H+h)*128+d][s].
// ---------------------------------------------------------------------------
__global__ __launch_bounds__(256) void transpose_v(
    const bf16* __restrict__ V, bf16* __restrict__ Vt, int rs)
{
  __shared__ bf16 sT[64 * 72];
  const int tid = threadIdx.x;
  const int si = blockIdx.x;
  const int di = blockIdx.y;
  const int bh = blockIdx.z;
  const int b  = bh >> 4, h = bh & 15;

  const bf16* src = V + (size_t)b * S_ * rs + (size_t)h * HD_ + di * 64;
  bf16*       dst = Vt + ((size_t)bh * HD_ + di * 64) * S_ + si * 64;

#pragma unroll
  for (int half = 0; half < 2; ++half) {
    int r  = half * 32 + (tid >> 3);
    int c0 = (tid & 7) * 8;
    bf16x8 v = *(const bf16x8*)(src + (size_t)(si * 64 + r) * rs + c0);
    *(bf16x8*)(sT + r * 72 + c0) = v;
  }
  __syncthreads();
#pragma unroll
  for (int half = 0; half < 2; ++half) {
    int dr = half * 32 + (tid >> 3);
    int c0 = (tid & 7) * 8;
    bf16x8 o;
#pragma unroll
    for (int j = 0; j < 8; ++j) o[j] = sT[(c0 + j) * 72 + dr];
    *(bf16x8*)(dst + (size_t)dr * S_ + c0) = o;
  }
}

// ---------------------------------------------------------------------------
// Flash attention fwd, causal. ABQ=128, ABK=64, 256 threads (4 waves).
// R8 XCD swizzle (all 16 q-blocks of a (b,h) column on one XCD; K/V/Vt
// L2-resident: FETCH 110->24.7MB measured) + R7 pipeline (K double-buffered
// LDS prefetch-after-barrier; V direct-to-register issued BEFORE the K
// prefetch so in-order vmcnt hides both: V L2-latency covered by QK+softmax,
// K prefetch in flight across the next barrier). One barrier per k-tile.
// S^T = K*Q^T (operand swap): softmax in-lane + 2 shuffles.
// sP [128q][72] wave-private A-layout P. Q/K row stride rs.
// ---------------------------------------------------------------------------
#define ABQ 128
#define ABK 64
#define SPS 72

__global__ __launch_bounds__(256) void attn_fwd(
    const bf16* __restrict__ Q, const bf16* __restrict__ K,
    const bf16* __restrict__ Vt, bf16* __restrict__ O, int rs)
{
  __shared__ bf16 sK[2][ABK * HD_];  // 2 x 16 KB
  __shared__ bf16 sP[ABQ * SPS];     // 18 KB   (total 50 KB)

  const int tid  = threadIdx.x;
  const int wave = tid >> 6, lane = tid & 63;
  const int quad = lane >> 4, l16 = lane & 15;

  // XCD-locality decode: col = b*H+h owns XCD col%8; qb heavy-first.
  const int lin   = (int)blockIdx.x;
  const int low3  = lin & 7;
  const int rest  = lin >> 3;
  const int qx    = rest & 15;
  const int colhi = rest >> 4;            // 0..3
  const int col   = low3 + (colhi << 3);  // 0..31
  const int b = col >> 4, h = col & 15;
  const int qb = 15 - qx;

  const bf16* Qh  = Q + (size_t)b * S_ * rs + (size_t)h * HD_;
  const bf16* Kh  = K + (size_t)b * S_ * rs + (size_t)h * HD_;
  const bf16* Vth = Vt + ((size_t)(b * H_ + h) * HD_) * S_;
  bf16*       Oh  = O + (size_t)b * S_ * D_ + (size_t)h * HD_;

  const int q0 = qb * ABQ;
  const int wq = wave * 32;
  const int wq_abs = q0 + wq;

  const int st_row[4] = { (0*256+tid)>>4, (1*256+tid)>>4, (2*256+tid)>>4, (3*256+tid)>>4 };
  const int st_cc[4]  = { (tid&15) ^ (st_row[0]&15), (tid&15) ^ (st_row[1]&15),
                          (tid&15) ^ (st_row[2]&15), (tid&15) ^ (st_row[3]&15) };

  // Q fragments (B operand; layout [n=l16][k=quad*8+j])
  bf16x8 qf[2][4];
#pragma unroll
  for (int i = 0; i < 2; ++i) {
    const bf16* rp = Qh + (size_t)(wq_abs + i * 16 + l16) * rs + quad * 8;
#pragma unroll
    for (int t = 0; t < 4; ++t) qf[i][t] = *(const bf16x8*)(rp + t * 32);
  }

  f32x4 o_acc[2][8];
#pragma unroll
  for (int i = 0; i < 2; ++i)
#pragma unroll
    for (int j = 0; j < 8; ++j) o_acc[i][j] = (f32x4)0.0f;
  float m_col[2] = {NEG_SENTINEL, NEG_SENTINEL};
  float l_col[2] = {0.0f, 0.0f};

  const int nkt = (q0 + ABQ) / ABK;   // 2*(qb+1)

  // prefetch tile 0 into buf 0
#pragma unroll
  for (int g = 0; g < 4; ++g)
    gload_lds16(Kh + (size_t)st_row[g] * rs + st_cc[g] * 8,
                (char*)sK[0] + (size_t)(g * 256 + tid) * 16);

  for (int kt = 0; kt < nkt; ++kt) {
    const int kk0 = kt * ABK;
    __syncthreads();   // drains the prefetch that flew through the prev compute

    const bool active = (kk0 <= wq_abs + 31);

    // 1) V direct loads FIRST (L2-local via swizzle; hidden by QK+softmax)
    bf16x8 vf[2][8];
    if (active) {
#pragma unroll
      for (int ks = 0; ks < 2; ++ks)
#pragma unroll
        for (int jd = 0; jd < 8; ++jd)
          vf[ks][jd] = *(const bf16x8*)(Vth + (size_t)(jd * 16 + l16) * S_ +
                                        kk0 + ks * 32 + quad * 8);
    }

    // 2) K prefetch for next tile (issued last -> in flight across barrier)
    if (kt + 1 < nkt) {
      const int nk0 = kk0 + ABK;
      char* dst = (char*)sK[(kt + 1) & 1];
#pragma unroll
      for (int g = 0; g < 4; ++g)
        gload_lds16(Kh + (size_t)(nk0 + st_row[g]) * rs + st_cc[g] * 8,
                    dst + (size_t)(g * 256 + tid) * 16);
    }

    const bf16* sKc = sK[kt & 1];

    if (active) {
      // S^T = K Q^T : lane holds key=(jt*16+quad*4+r), q-col=l16
      f32x4 st[2][4];
#pragma unroll
      for (int jt = 0; jt < 4; ++jt) {
        bf16x8 kf[4];
#pragma unroll
        for (int t = 0; t < 4; ++t) {
          int pos = (t * 4 + quad) ^ l16;
          kf[t] = *(const bf16x8*)(sKc + (jt * 16 + l16) * HD_ + pos * 8);
        }
#pragma unroll
        for (int i = 0; i < 2; ++i) {
          f32x4 a = (f32x4)0.0f;
#pragma unroll
          for (int t = 0; t < 4; ++t) a = mfma16(kf[t], qf[i][t], a);
          st[i][jt] = a;
        }
      }

      // causal mask only where the tile crosses this wave's diagonal
      if (kk0 + 63 > wq_abs) {
#pragma unroll
        for (int i = 0; i < 2; ++i) {
          int qcol = wq_abs + i * 16 + l16;
#pragma unroll
          for (int jt = 0; jt < 4; ++jt)
#pragma unroll
            for (int r = 0; r < 4; ++r) {
              int key = kk0 + jt * 16 + quad * 4 + r;
              if (key > qcol) st[i][jt][r] = NEG_SENTINEL;
            }
        }
      }

      // online softmax (base-2): in-lane tree + 2 shuffles per reduction
#pragma unroll
      for (int i = 0; i < 2; ++i) {
        float mx = NEG_SENTINEL;
#pragma unroll
        for (int jt = 0; jt < 4; ++jt)
#pragma unroll
          for (int r = 0; r < 4; ++r) mx = fmaxf(mx, st[i][jt][r]);
        mx = fmaxf(mx, __shfl_xor(mx, 16, 64));
        mx = fmaxf(mx, __shfl_xor(mx, 32, 64));
        float m_new = fmaxf(m_col[i], mx);
        float alpha = exp2f(m_col[i] - m_new);
        float ts = 0.0f;
#pragma unroll
        for (int jt = 0; jt < 4; ++jt) {
          bf16x4 pk;
#pragma unroll
          for (int r = 0; r < 4; ++r) {
            float p = exp2f(st[i][jt][r] - m_new);
            ts += p;
            pk[r] = (bf16)p;
          }
          *(bf16x4*)(sP + (wq + i * 16 + l16) * SPS + jt * 16 + quad * 4) = pk;
        }
        ts += __shfl_xor(ts, 16, 64);
        ts += __shfl_xor(ts, 32, 64);
        l_col[i] = l_col[i] * alpha + ts;
        m_col[i] = m_new;
#pragma unroll
        for (int r = 0; r < 4; ++r) {
          float av = __shfl(alpha, quad * 4 + r, 64);
#pragma unroll
          for (int jd = 0; jd < 8; ++jd) o_acc[i][jd][r] *= av;
        }
      }
      // sP rows are wave-private: same-wave LDS RAW needs no barrier.

      // O += P V : P from sP (A-layout), V from registers
#pragma unroll
      for (int ks = 0; ks < 2; ++ks) {
        bf16x8 pf[2];
#pragma unroll
        for (int i = 0; i < 2; ++i)
          pf[i] = *(const bf16x8*)(sP + (wq + i * 16 + l16) * SPS + ks * 32 + quad * 8);
#pragma unroll
        for (int i = 0; i < 2; ++i)
#pragma unroll
          for (int jd = 0; jd < 8; ++jd)
            o_acc[i][jd] = mfma16(pf[i], vf[ks][jd], o_acc[i][jd]);
      }
    }
  }

  // epilogue: fetch denom from q-col lanes, store ctx (dense stride D_)
#pragma unroll
  for (int i = 0; i < 2; ++i)
#pragma unroll
    for (int r = 0; r < 4; ++r) {
      float lv = __shfl(l_col[i], quad * 4 + r, 64);
      float inv_l = 1.0f / lv;
      int row = wq_abs + i * 16 + quad * 4 + r;
#pragma unroll
      for (int jd = 0; jd < 8; ++jd) {
        int colo = jd * 16 + l16;
        Oh[(size_t)row * D_ + colo] = (bf16)(o_acc[i][jd][r] * inv_l);
      }
    }
}

// ---------------------------------------------------------------------------
extern "C" void kernel_launch(void* const* d_in, const int* in_sizes, int n_in,
                              void* d_out, int out_size, void* d_ws, size_t ws_size,
                              hipStream_t stream) {
  const float* x    = (const float*)d_in[0];
  const float* Wq   = (const float*)d_in[1];
  const float* Wk   = (const float*)d_in[2];
  const float* Wv   = (const float*)d_in[3];
  const float* Wo   = (const float*)d_in[4];
  const float* cosT = (const float*)d_in[5];
  const float* sinT = (const float*)d_in[6];
  float* out = (float*)d_out;

  const size_t NE = (size_t)B_ * S_ * D_;   // 8,388,608
  const size_t WE = (size_t)D_ * D_;        // 4,194,304
  const int M = B_ * S_;
  const int cvtX = (int)(NE / 1024);
  const int cvtW = (int)(WE / 1024);

  if (ws_size >= (size_t)92274688) {
    // ---- fused-QKV path (88 MB): QKV(48) | xb(16) | Wqkv->ctx+Wo_b(24) ----
    bf16* QKV   = (bf16*)d_ws;              // (4096, 6144) row-major
    bf16* xb    = QKV + (size_t)M * 6144;
    bf16* Wqkv  = xb + NE;
    bf16* ctx   = Wqkv;                     // reuse after QKV GEMM
    bf16* Wob   = Wqkv + 2 * WE;
    bf16* Vt    = xb;                       // reuse after QKV GEMM

    cvt_f32_bf16<<<cvtX, 256, 0, stream>>>(x, xb);
    cvt_f32_bf16<<<cvtW, 256, 0, stream>>>(Wq, Wqkv);
    cvt_f32_bf16<<<cvtW, 256, 0, stream>>>(Wk, Wqkv + WE);
    cvt_f32_bf16<<<cvtW, 256, 0, stream>>>(Wv, Wqkv + 2 * WE);
    gemm_xwt<bf16><<<dim3(48, 32), 256, 0, stream>>>(xb, Wqkv, QKV, M, 3 * D_, D_, 3 * D_);
    rope_qk<<<(B_ * S_ * H_ * 64) / 256, 256, 0, stream>>>(QKV, QKV + D_, cosT, sinT, 3 * D_);
    transpose_v<<<dim3(32, 2, 32), 256, 0, stream>>>(QKV + 2 * D_, Vt, 3 * D_);
    attn_fwd<<<512, 256, 0, stream>>>(QKV, QKV + D_, Vt, ctx, 3 * D_);
    cvt_f32_bf16<<<cvtW, 256, 0, stream>>>(Wo, Wob);
    gemm_xwt<float><<<dim3(16, 32), 256, 0, stream>>>(ctx, Wob, out, M, D_, D_, D_);
  } else {
    // ---- fallback (72 MB): R8 sequence with the new pipelined attn ----
    bf16* Qb    = (bf16*)d_ws;
    bf16* Kb    = Qb + NE;
    bf16* Vb    = Kb + NE;
    bf16* Cb    = Vb + NE;                  // bf16(x) -> later Vt
    bf16* Wslot = Cb + NE;

    cvt_f32_bf16<<<cvtX, 256, 0, stream>>>(x, Cb);
    cvt_f32_bf16<<<cvtW, 256, 0, stream>>>(Wq, Wslot);
    gemm_xwt<bf16><<<dim3(16, 32), 256, 0, stream>>>(Cb, Wslot, Qb, M, D_, D_, D_);
    cvt_f32_bf16<<<cvtW, 256, 0, stream>>>(Wk, Wslot);
    gemm_xwt<bf16><<<dim3(16, 32), 256, 0, stream>>>(Cb, Wslot, Kb, M, D_, D_, D_);
    cvt_f32_bf16<<<cvtW, 256, 0, stream>>>(Wv, Wslot);
    gemm_xwt<bf16><<<dim3(16, 32), 256, 0, stream>>>(Cb, Wslot, Vb, M, D_, D_, D_);
    rope_qk<<<(B_ * S_ * H_ * 64) / 256, 256, 0, stream>>>(Qb, Kb, cosT, sinT, D_);
    transpose_v<<<dim3(32, 2, 32), 256, 0, stream>>>(Vb, Cb, D_);
    attn_fwd<<<512, 256, 0, stream>>>(Qb, Kb, Cb, Vb, D_);
    cvt_f32_bf16<<<cvtW, 256, 0, stream>>>(Wo, Wslot);
    gemm_xwt<float><<<dim3(16, 32), 256, 0, stream>>>(Vb, Wslot, out, M, D_, D_, D_);
  }
}

// Round 10
// 406.054 us; speedup vs baseline: 1.3592x; 1.3592x over previous
//
#include <hip/hip_runtime.h>
#include <cstdint>
#include <cmath>

#define B_ 2
#define S_ 2048
#define D_ 2048
#define H_ 16
#define HD_ 128

#define NEG_SENTINEL -1.0e30f

typedef __bf16 bf16;
typedef __attribute__((ext_vector_type(4))) __bf16 bf16x4;
typedef __attribute__((ext_vector_type(8))) __bf16 bf16x8;
typedef __attribute__((ext_vector_type(4))) float f32x4;

__device__ __forceinline__ void gload_lds16(const void* g, void* l) {
  __builtin_amdgcn_global_load_lds(
      (const __attribute__((address_space(1))) unsigned int*)g,
      (__attribute__((address_space(3))) unsigned int*)l, 16, 0, 0);
}

__device__ __forceinline__ f32x4 mfma16(bf16x8 a, bf16x8 b, f32x4 c) {
  return __builtin_amdgcn_mfma_f32_16x16x32_bf16(a, b, c, 0, 0, 0);
}

// ---------------------------------------------------------------------------
// fp32 -> bf16 convert. One thread = 4 elements.
// ---------------------------------------------------------------------------
__global__ __launch_bounds__(256) void cvt_f32_bf16(
    const float* __restrict__ in, bf16* __restrict__ out)
{
  int i = blockIdx.x * 256 + threadIdx.x;
  f32x4 v = ((const f32x4*)in)[i];
  bf16x4 o;
#pragma unroll
  for (int j = 0; j < 4; ++j) o[j] = (bf16)v[j];
  ((bf16x4*)out)[i] = o;
}

// ---------------------------------------------------------------------------
// GEMM: C[m][n] = sum_k A[m][k] * W[n][k], bf16 in, fp32 acc, OT out,
// C row stride ldc. 128x128 tile, BK=64, XOR chunk swizzle. (verified R3)
// ---------------------------------------------------------------------------
#define GTM 128
#define GTN 128
#define GBK 64

template <typename OT>
__global__ __launch_bounds__(256) void gemm_xwt(
    const bf16* __restrict__ A, const bf16* __restrict__ W, OT* __restrict__ C,
    int M, int N, int K, int ldc)
{
  __shared__ bf16 sA[GTM * GBK];
  __shared__ bf16 sB[GTN * GBK];
  const int tid  = threadIdx.x;
  const int wave = tid >> 6, lane = tid & 63;
  const int quad = lane >> 4, l16 = lane & 15;
  const int tm = blockIdx.y * GTM;
  const int tn = blockIdx.x * GTN;
  const int wm = (wave >> 1) * 64, wn = (wave & 1) * 64;

  f32x4 acc[4][4];
#pragma unroll
  for (int i = 0; i < 4; ++i)
#pragma unroll
    for (int j = 0; j < 4; ++j) acc[i][j] = (f32x4)0.0f;

  for (int k0 = 0; k0 < K; k0 += GBK) {
    __syncthreads();
#pragma unroll
    for (int g = 0; g < 4; ++g) {
      int gb  = (g * 4 + wave) * 64;
      int p   = gb + lane;
      int row = p >> 3, pos = p & 7;
      int cc  = pos ^ (row & 7);
      gload_lds16(A + (size_t)(tm + row) * K + k0 + cc * 8, (char*)sA + (size_t)gb * 16);
      gload_lds16(W + (size_t)(tn + row) * K + k0 + cc * 8, (char*)sB + (size_t)gb * 16);
    }
    __syncthreads();

#pragma unroll
    for (int t = 0; t < 2; ++t) {
      bf16x8 af[4], bfr[4];
#pragma unroll
      for (int i = 0; i < 4; ++i) {
        int rowa = wm + i * 16 + l16;
        int posa = (t * 4 + quad) ^ (rowa & 7);
        af[i] = *(const bf16x8*)(sA + rowa * GBK + posa * 8);
        int rowb = wn + i * 16 + l16;
        int posb = (t * 4 + quad) ^ (rowb & 7);
        bfr[i] = *(const bf16x8*)(sB + rowb * GBK + posb * 8);
      }
#pragma unroll
      for (int i = 0; i < 4; ++i)
#pragma unroll
        for (int j = 0; j < 4; ++j)
          acc[i][j] = mfma16(af[i], bfr[j], acc[i][j]);
    }
  }

#pragma unroll
  for (int i = 0; i < 4; ++i)
#pragma unroll
    for (int r = 0; r < 4; ++r) {
      int row = tm + wm + i * 16 + quad * 4 + r;
#pragma unroll
      for (int j = 0; j < 4; ++j) {
        int col = tn + wn + j * 16 + l16;
        C[(size_t)row * ldc + col] = (OT)acc[i][j][r];
      }
    }
}

// ---------------------------------------------------------------------------
// RoPE in-place; Q pre-scaled by 1/sqrt(HD)*log2(e). Row stride rs.
// ---------------------------------------------------------------------------
__global__ __launch_bounds__(256) void rope_qk(
    bf16* __restrict__ Q, bf16* __restrict__ Kk,
    const float* __restrict__ cosT, const float* __restrict__ sinT, int rs)
{
  const float kappa = 0.08838834764831845f * 1.4426950408889634f;
  int t = blockIdx.x * 256 + threadIdx.x;
  int d = t & 63;
  int h = (t >> 6) & (H_ - 1);
  int s = (t >> 10) & (S_ - 1);
  int b = t >> 21;
  size_t base = ((size_t)(b * S_ + s)) * rs + (size_t)h * HD_;
  float c1 = cosT[s * HD_ + d];
  float s1 = sinT[s * HD_ + d];
  float c2 = cosT[s * HD_ + d + 64];
  float s2 = sinT[s * HD_ + d + 64];
  {
    float x1 = (float)Q[base + d], x2 = (float)Q[base + d + 64];
    Q[base + d]      = (bf16)((x1 * c1 - x2 * s1) * kappa);
    Q[base + d + 64] = (bf16)((x2 * c2 + x1 * s2) * kappa);
  }
  {
    float x1 = (float)Kk[base + d], x2 = (float)Kk[base + d + 64];
    Kk[base + d]      = (bf16)(x1 * c1 - x2 * s1);
    Kk[base + d + 64] = (bf16)(x2 * c2 + x1 * s2);
  }
}

// ---------------------------------------------------------------------------
// V transpose: V[b][s][...] (row stride rs) -> Vt[(b*H+h)*128+d][s].
// ---------------------------------------------------------------------------
__global__ __launch_bounds__(256) void transpose_v(
    const bf16* __restrict__ V, bf16* __restrict__ Vt, int rs)
{
  __shared__ bf16 sT[64 * 72];
  const int tid = threadIdx.x;
  const int si = blockIdx.x;
  const int di = blockIdx.y;
  const int bh = blockIdx.z;
  const int b  = bh >> 4, h = bh & 15;

  const bf16* src = V + (size_t)b * S_ * rs + (size_t)h * HD_ + di * 64;
  bf16*       dst = Vt + ((size_t)bh * HD_ + di * 64) * S_ + si * 64;

#pragma unroll
  for (int half = 0; half < 2; ++half) {
    int r  = half * 32 + (tid >> 3);
    int c0 = (tid & 7) * 8;
    bf16x8 v = *(const bf16x8*)(src + (size_t)(si * 64 + r) * rs + c0);
    *(bf16x8*)(sT + r * 72 + c0) = v;
  }
  __syncthreads();
#pragma unroll
  for (int half = 0; half < 2; ++half) {
    int dr = half * 32 + (tid >> 3);
    int c0 = (tid & 7) * 8;
    bf16x8 o;
#pragma unroll
    for (int j = 0; j < 8; ++j) o[j] = sT[(c0 + j) * 72 + dr];
    *(bf16x8*)(dst + (size_t)dr * S_ + c0) = o;
  }
}

// ---------------------------------------------------------------------------
// Flash attention fwd, causal. BALANCED-PAIR version of the measured-best R8
// structure (staged sK+sVT via global_load_lds, 2 barriers/iter, S^T=K*Q^T
// softmax, wave-private sP, XCD swizzle).
// ABQ=64 (4 waves x 16 q-rows), 32 q-tiles per column; each block processes
// the pair (qt, 31-qt) sequentially -> every block runs exactly 33 k-tile
// iterations: zero tail, no load imbalance (R8's Occupancy=6.8% diagnosis).
// Grid 512 = 32 columns x 16 pairs, XCD-local decode unchanged.
// LDS 41 KB, VGPR ~120 -> 3 waves/SIMD.
// ---------------------------------------------------------------------------
#define ABK 64
#define SPS 72

__global__ __launch_bounds__(256) void attn_fwd(
    const bf16* __restrict__ Q, const bf16* __restrict__ K,
    const bf16* __restrict__ Vt, bf16* __restrict__ O, int rs)
{
  __shared__ bf16 sK[ABK * HD_];     // 16 KB
  __shared__ bf16 sVT[HD_ * ABK];    // 16 KB
  __shared__ bf16 sP[64 * SPS];      // 9 KB   (total 41 KB)

  const int tid  = threadIdx.x;
  const int wave = tid >> 6, lane = tid & 63;
  const int quad = lane >> 4, l16 = lane & 15;

  // XCD-locality decode: col = b*H+h owns XCD col%8.
  const int lin   = (int)blockIdx.x;
  const int low3  = lin & 7;
  const int rest  = lin >> 3;
  const int pairx = rest & 15;            // 0..15
  const int colhi = rest >> 4;            // 0..3
  const int col   = low3 + (colhi << 3);  // 0..31
  const int b = col >> 4, h = col & 15;

  const bf16* Qh  = Q + (size_t)b * S_ * rs + (size_t)h * HD_;
  const bf16* Kh  = K + (size_t)b * S_ * rs + (size_t)h * HD_;
  const bf16* Vth = Vt + ((size_t)(b * H_ + h) * HD_) * S_;
  bf16*       Oh  = O + (size_t)b * S_ * D_ + (size_t)h * HD_;

  const int wq = wave * 16;

  // balanced pair: (pairx) and (31-pairx) -> (qt+1)+(32-qt) = 33 iters/block
#pragma unroll 1
  for (int seg = 0; seg < 2; ++seg) {
    const int qt = seg == 0 ? pairx : 31 - pairx;
    const int q0 = qt * 64;
    const int wq_abs = q0 + wq;

    // Q fragments (B operand; layout [n=l16][k=quad*8+j])
    bf16x8 qf[4];
    {
      const bf16* rp = Qh + (size_t)(wq_abs + l16) * rs + quad * 8;
#pragma unroll
      for (int t = 0; t < 4; ++t) qf[t] = *(const bf16x8*)(rp + t * 32);
    }

    f32x4 o_acc[8];
#pragma unroll
    for (int j = 0; j < 8; ++j) o_acc[j] = (f32x4)0.0f;
    float m_col = NEG_SENTINEL;
    float l_col = 0.0f;

    const int nkt = qt + 1;
#pragma unroll 1
    for (int kt = 0; kt < nkt; ++kt) {
      const int kk0 = kt * ABK;
      __syncthreads();   // all waves done with sK/sVT before restage

      // stage K: 1024 chunks over 256 threads, pos = cc ^ (row&15)
#pragma unroll
      for (int g = 0; g < 4; ++g) {
        int p   = g * 256 + tid;
        int row = p >> 4, pos = p & 15;
        int cc  = pos ^ (row & 15);
        gload_lds16(Kh + (size_t)(kk0 + row) * rs + cc * 8, (char*)sK + (size_t)p * 16);
      }
      // stage V^T from Vt: 1024 chunks, pos = cc ^ (d&7)
#pragma unroll
      for (int g = 0; g < 4; ++g) {
        int p  = g * 256 + tid;
        int d  = p >> 3, pos = p & 7;
        int cc = pos ^ (d & 7);
        gload_lds16(Vth + (size_t)d * S_ + kk0 + cc * 8, (char*)sVT + (size_t)p * 16);
      }
      __syncthreads();   // drain global_load_lds

      // waves whose 16 q-rows are entirely below this key tile skip compute
      if (kk0 <= wq_abs + 15) {
        // S^T = K Q^T : lane holds key=(jt*16+quad*4+r), q-col=l16
        f32x4 st[4];
#pragma unroll
        for (int jt = 0; jt < 4; ++jt) {
          bf16x8 kf[4];
#pragma unroll
          for (int t = 0; t < 4; ++t) {
            int pos = (t * 4 + quad) ^ l16;
            kf[t] = *(const bf16x8*)(sK + (jt * 16 + l16) * HD_ + pos * 8);
          }
          f32x4 a = (f32x4)0.0f;
#pragma unroll
          for (int t = 0; t < 4; ++t) a = mfma16(kf[t], qf[t], a);
          st[jt] = a;
        }

        // causal mask only where the tile crosses this wave's diagonal
        if (kk0 + 63 > wq_abs) {
          int qcol = wq_abs + l16;
#pragma unroll
          for (int jt = 0; jt < 4; ++jt)
#pragma unroll
            for (int r = 0; r < 4; ++r) {
              int key = kk0 + jt * 16 + quad * 4 + r;
              if (key > qcol) st[jt][r] = NEG_SENTINEL;
            }
        }

        // online softmax (base-2): in-lane tree + 2 shuffles per reduction
        float mx = NEG_SENTINEL;
#pragma unroll
        for (int jt = 0; jt < 4; ++jt)
#pragma unroll
          for (int r = 0; r < 4; ++r) mx = fmaxf(mx, st[jt][r]);
        mx = fmaxf(mx, __shfl_xor(mx, 16, 64));
        mx = fmaxf(mx, __shfl_xor(mx, 32, 64));
        float m_new = fmaxf(m_col, mx);
        float alpha = exp2f(m_col - m_new);
        float ts = 0.0f;
#pragma unroll
        for (int jt = 0; jt < 4; ++jt) {
          bf16x4 pk;
#pragma unroll
          for (int r = 0; r < 4; ++r) {
            float p = exp2f(st[jt][r] - m_new);
            ts += p;
            pk[r] = (bf16)p;
          }
          *(bf16x4*)(sP + (wq + l16) * SPS + jt * 16 + quad * 4) = pk;
        }
        ts += __shfl_xor(ts, 16, 64);
        ts += __shfl_xor(ts, 32, 64);
        l_col = l_col * alpha + ts;
        m_col = m_new;
#pragma unroll
        for (int r = 0; r < 4; ++r) {
          float av = __shfl(alpha, quad * 4 + r, 64);
#pragma unroll
          for (int jd = 0; jd < 8; ++jd) o_acc[jd][r] *= av;
        }
        // sP rows are wave-private: same-wave LDS RAW needs no barrier.

        // O += P V  (two 32-key steps)
#pragma unroll
        for (int ks = 0; ks < 2; ++ks) {
          bf16x8 pf = *(const bf16x8*)(sP + (wq + l16) * SPS + ks * 32 + quad * 8);
#pragma unroll
          for (int jd = 0; jd < 8; ++jd) {
            int pos = (ks * 4 + quad) ^ (l16 & 7);
            bf16x8 vf = *(const bf16x8*)(sVT + (jd * 16 + l16) * ABK + pos * 8);
            o_acc[jd] = mfma16(pf, vf, o_acc[jd]);
          }
        }
      }
    }

    // epilogue: fetch denom from q-col lanes, store ctx (dense stride D_)
#pragma unroll
    for (int r = 0; r < 4; ++r) {
      float lv = __shfl(l_col, quad * 4 + r, 64);
      float inv_l = 1.0f / lv;
      int row = wq_abs + quad * 4 + r;
#pragma unroll
      for (int jd = 0; jd < 8; ++jd) {
        int colo = jd * 16 + l16;
        Oh[(size_t)row * D_ + colo] = (bf16)(o_acc[jd][r] * inv_l);
      }
    }
  }
}

// ---------------------------------------------------------------------------
extern "C" void kernel_launch(void* const* d_in, const int* in_sizes, int n_in,
                              void* d_out, int out_size, void* d_ws, size_t ws_size,
                              hipStream_t stream) {
  const float* x    = (const float*)d_in[0];
  const float* Wq   = (const float*)d_in[1];
  const float* Wk   = (const float*)d_in[2];
  const float* Wv   = (const float*)d_in[3];
  const float* Wo   = (const float*)d_in[4];
  const float* cosT = (const float*)d_in[5];
  const float* sinT = (const float*)d_in[6];
  float* out = (float*)d_out;

  const size_t NE = (size_t)B_ * S_ * D_;   // 8,388,608
  const size_t WE = (size_t)D_ * D_;        // 4,194,304
  const int M = B_ * S_;
  const int cvtX = (int)(NE / 1024);
  const int cvtW = (int)(WE / 1024);

  if (ws_size >= (size_t)92274688) {
    // ---- fused-QKV path (88 MB): QKV(48) | xb(16) | Wqkv->ctx+Wo_b(24) ----
    bf16* QKV   = (bf16*)d_ws;              // (4096, 6144) row-major
    bf16* xb    = QKV + (size_t)M * 6144;
    bf16* Wqkv  = xb + NE;
    bf16* ctx   = Wqkv;                     // reuse after QKV GEMM
    bf16* Wob   = Wqkv + 2 * WE;
    bf16* Vt    = xb;                       // reuse after QKV GEMM

    cvt_f32_bf16<<<cvtX, 256, 0, stream>>>(x, xb);
    cvt_f32_bf16<<<cvtW, 256, 0, stream>>>(Wq, Wqkv);
    cvt_f32_bf16<<<cvtW, 256, 0, stream>>>(Wk, Wqkv + WE);
    cvt_f32_bf16<<<cvtW, 256, 0, stream>>>(Wv, Wqkv + 2 * WE);
    gemm_xwt<bf16><<<dim3(48, 32), 256, 0, stream>>>(xb, Wqkv, QKV, M, 3 * D_, D_, 3 * D_);
    rope_qk<<<(B_ * S_ * H_ * 64) / 256, 256, 0, stream>>>(QKV, QKV + D_, cosT, sinT, 3 * D_);
    transpose_v<<<dim3(32, 2, 32), 256, 0, stream>>>(QKV + 2 * D_, Vt, 3 * D_);
    attn_fwd<<<512, 256, 0, stream>>>(QKV, QKV + D_, Vt, ctx, 3 * D_);
    cvt_f32_bf16<<<cvtW, 256, 0, stream>>>(Wo, Wob);
    gemm_xwt<float><<<dim3(16, 32), 256, 0, stream>>>(ctx, Wob, out, M, D_, D_, D_);
  } else {
    // ---- fallback (72 MB): separate GEMMs, same attn ----
    bf16* Qb    = (bf16*)d_ws;
    bf16* Kb    = Qb + NE;
    bf16* Vb    = Kb + NE;
    bf16* Cb    = Vb + NE;                  // bf16(x) -> later Vt
    bf16* Wslot = Cb + NE;

    cvt_f32_bf16<<<cvtX, 256, 0, stream>>>(x, Cb);
    cvt_f32_bf16<<<cvtW, 256, 0, stream>>>(Wq, Wslot);
    gemm_xwt<bf16><<<dim3(16, 32), 256, 0, stream>>>(Cb, Wslot, Qb, M, D_, D_, D_);
    cvt_f32_bf16<<<cvtW, 256, 0, stream>>>(Wk, Wslot);
    gemm_xwt<bf16><<<dim3(16, 32), 256, 0, stream>>>(Cb, Wslot, Kb, M, D_, D_, D_);
    cvt_f32_bf16<<<cvtW, 256, 0, stream>>>(Wv, Wslot);
    gemm_xwt<bf16><<<dim3(16, 32), 256, 0, stream>>>(Cb, Wslot, Vb, M, D_, D_, D_);
    rope_qk<<<(B_ * S_ * H_ * 64) / 256, 256, 0, stream>>>(Qb, Kb, cosT, sinT, D_);
    transpose_v<<<dim3(32, 2, 32), 256, 0, stream>>>(Vb, Cb, D_);
    attn_fwd<<<512, 256, 0, stream>>>(Qb, Kb, Cb, Vb, D_);
    cvt_f32_bf16<<<cvtW, 256, 0, stream>>>(Wo, Wslot);
    gemm_xwt<float><<<dim3(16, 32), 256, 0, stream>>>(Vb, Wslot, out, M, D_, D_, D_);
  }
}